// Round 10
// baseline (6113.305 us; speedup 1.0000x reference)
//
#include <hip/hip_runtime.h>
#include <hip/hip_bf16.h>

typedef unsigned short u16;
typedef unsigned char u8;

// Problem constants: B_=2, T=4096, DIM=1024, HEADS=16, DH=64, NH(rounds)=8,
// NB(buckets)=64, BUCKET=64, merged batch-heads M=32, chunks/merged-head=512.
//
// ROUND 10: replicate the np-fp32 reference arithmetic on the bucket-decision
// path. Evidence (r7 vs r9: fp64 hash == fp32 hash bit-identically; r5 naive
// == r7 optimized): exactly ~one near-tie token's bucket differs from the
// fp32 np reference. Fix: qk GEMM in fp32 FMA ascending-k (matches BLAS
// sgemm's per-element chain) and hash in fp32 FMA ascending-f from the SAME
// fp32 qk (matches np einsum / sgemm). Inputs confirmed fp32 (round-1 NaN
// evidence); output fp32 (round-7 13x error drop).

// ---- scratch in static device globals ----
__device__ static float g_qk32[32u * 4096u * 64u];   // 32 MB [m][t][d]
__device__ static float g_v32 [32u * 4096u * 64u];   // 32 MB
__device__ static float g_ctx [2u * 4096u * 1024u];  // 32 MB [b][t][head*64+d]
__device__ static float g_logits[32u * 8u * 4096u];  //  4 MB [m][h][t]
__device__ static float g_probs [32u * 8u * 4096u];  //  4 MB
__device__ static u16   g_st  [32u * 8u * 4096u];    //  2 MB sorted token idx
__device__ static u8    g_bkt [32u * 8u * 4096u];    //  1 MB bucket ids

// ---------------------------------------------------------------------------
// Kernel 1: fused qkv GEMM (fp32 FMA, ascending k — BLAS-sgemm-equivalent
// per-element chain) + fp32 LSH hash (sequential ascending f, FMA).
// grid (128, 32): bn<16 -> qk head bn (+ hashing), bn>=16 -> v head bn-16.
// C tile 64x64, K-step 32, 256 threads.
// ---------------------------------------------------------------------------
__global__ __launch_bounds__(256) void qkv_hash_gemm(
    const float* __restrict__ x, const float* __restrict__ w_qk,
    const float* __restrict__ w_v, const float* __restrict__ rot_in)
{
    __shared__ __align__(16) float As[32][68];   // [kk][row]
    __shared__ __align__(16) float Ws[32][68];   // [kk][col]
    __shared__ float qs32[64][65];               // fp32 qk tile [t_local][f]
    __shared__ float rotS[16384];                // rotations flat [f][h][i]
    const int tid = threadIdx.x;
    const int bm = blockIdx.x;
    const int bn = blockIdx.y;
    const bool is_v = bn >= 16;
    const float* __restrict__ w = is_v ? w_v : w_qk;
    const int head = is_v ? bn - 16 : bn;
    const int ncol0 = head * 64;
    const int row0 = bm * 64;
    const int tx = tid & 15, ty = tid >> 4;
    const int lr = tid >> 2;          // loader row 0..63
    const int lk = (tid & 3) * 8;     // loader k offset {0,8,16,24}
    float acc[4][4] = {};

    for (int k0 = 0; k0 < 1024; k0 += 32) {
        float av[8], wv[8];
        *(float4*)&av[0] = *(const float4*)(x + (size_t)(row0 + lr) * 1024 + k0 + lk);
        *(float4*)&av[4] = *(const float4*)(x + (size_t)(row0 + lr) * 1024 + k0 + lk + 4);
        *(float4*)&wv[0] = *(const float4*)(w + (size_t)(ncol0 + lr) * 1024 + k0 + lk);
        *(float4*)&wv[4] = *(const float4*)(w + (size_t)(ncol0 + lr) * 1024 + k0 + lk + 4);
        __syncthreads();
#pragma unroll
        for (int q = 0; q < 8; q++) { As[lk + q][lr] = av[q]; Ws[lk + q][lr] = wv[q]; }
        __syncthreads();
        // per-element: acc = fma(a_k, b_k, acc), k strictly ascending
#pragma unroll
        for (int kk = 0; kk < 32; kk++) {
            const float4 a = *(const float4*)&As[kk][ty * 4];
            const float4 b = *(const float4*)&Ws[kk][tx * 4];
            const float aa[4] = {a.x, a.y, a.z, a.w};
            const float bb[4] = {b.x, b.y, b.z, b.w};
#pragma unroll
            for (int i = 0; i < 4; i++)
#pragma unroll
                for (int j = 0; j < 4; j++)
                    acc[i][j] = fmaf(aa[i], bb[j], acc[i][j]);
        }
    }
    const int b_ = row0 >> 12;           // batch (tile never straddles)
    const int m = b_ * 16 + head;
    float* __restrict__ dst = is_v ? g_v32 : g_qk32;
#pragma unroll
    for (int i = 0; i < 4; i++) {
        const int t = (row0 & 4095) + ty * 4 + i;
#pragma unroll
        for (int j = 0; j < 4; j++)
            dst[(((size_t)m * 4096 + t) << 6) + tx * 4 + j] = acc[i][j];
    }
    if (is_v) return;                    // uniform per block

    // --- fp32 hashing: argmax([rot, -rot]), first occurrence; sequential
    // --- ascending-f FMA chain from the same fp32 qk values ---
#pragma unroll
    for (int i = 0; i < 4; i++)
#pragma unroll
        for (int j = 0; j < 4; j++)
            qs32[ty * 4 + i][tx * 4 + j] = acc[i][j];
    for (int idx = tid; idx < 16384; idx += 256)
        rotS[idx] = rot_in[idx];
    __syncthreads();
    const int tl = tid & 63;
    const int hq = tid >> 6;             // 0..3; handles rounds hq and hq+4
    const float* __restrict__ qrow = qs32[tl];
    for (int hh = hq; hh < 8; hh += 4) {
        float bp = -3.4e38f; int ip = 0;
        float mn = 3.4e38f;  int im = 0;
        for (int i = 0; i < 32; i++) {
            float s = 0.f;
            for (int f = 0; f < 64; f++)
                s = fmaf(qrow[f], rotS[f * 256 + hh * 32 + i], s);
            if (s > bp) { bp = s; ip = i; }
            if (s < mn) { mn = s; im = i; }
        }
        const int bi = (-mn > bp) ? (32 + im) : ip;
        g_bkt[((size_t)m * 8 + hh) * 4096 + (row0 & 4095) + tl] = (u8)bi;
    }
}

// ---------------------------------------------------------------------------
// Kernel 2: per-(m,h) stable counting sort of 4096 tokens into 64 buckets.
// ---------------------------------------------------------------------------
__global__ __launch_bounds__(256) void sort_kernel()
{
    __shared__ u16 hist[256 * 64];   // [chunk][bucket]
    __shared__ u8 bkt[4096];
    __shared__ int rowsum[64];
    __shared__ int rowbase[64];
    const int tid = threadIdx.x;
    const int mh = blockIdx.x;
    const u8* __restrict__ src = g_bkt + (size_t)mh * 4096;
    for (int i = tid; i < 4096; i += 256) bkt[i] = src[i];
    for (int i = tid; i < 16384; i += 256) hist[i] = 0;
    __syncthreads();
#pragma unroll
    for (int k = 0; k < 16; k++) {
        const int t = tid * 16 + k;
        hist[tid * 64 + (bkt[t] & 63)]++;  // own row -> race-free, stable
    }
    __syncthreads();
    if (tid < 64) {
        int s = 0;
        for (int c = 0; c < 256; c++) s += hist[c * 64 + tid];
        rowsum[tid] = s;
    }
    __syncthreads();
    if (tid == 0) {
        int acc = 0;
        for (int b = 0; b < 64; b++) { rowbase[b] = acc; acc += rowsum[b]; }
    }
    __syncthreads();
    if (tid < 64) {
        int run = rowbase[tid];
        for (int c = 0; c < 256; c++) {
            const int tmp = hist[c * 64 + tid];
            hist[c * 64 + tid] = (u16)run;
            run += tmp;
        }
    }
    __syncthreads();
    u16* __restrict__ dst = g_st + (size_t)mh * 4096;
#pragma unroll
    for (int k = 0; k < 16; k++) {
        const int t = tid * 16 + k;
        const int b = bkt[t] & 63;
        const int pos = hist[tid * 64 + b]++;
        dst[pos & 4095] = (u16)t;
    }
}

// ---------------------------------------------------------------------------
// Kernel 3: zero the ctx accumulator (32 MB).
// ---------------------------------------------------------------------------
__global__ __launch_bounds__(256) void zero_ctx()
{
    ((float4*)g_ctx)[(size_t)blockIdx.x * 256 + threadIdx.x] =
        float4{0.f, 0.f, 0.f, 0.f};
}

// ---------------------------------------------------------------------------
// Kernel 4: per-chunk attention logits (logsumexp over 128 keys).
// Block 256 = 64 rows x 4 col-groups. grid 16384 = 32*512.
// ---------------------------------------------------------------------------
__global__ __launch_bounds__(256) void attn_lse()
{
    __shared__ __align__(16) float ks[128 * 68];
    __shared__ float rnorm[128];
    __shared__ int tk[128];
    __shared__ float part_m[256];
    __shared__ float part_s[256];
    const int tid = threadIdx.x;
    const int bid = blockIdx.x;
    const int m = bid >> 9, c = bid & 511;
    const int h = c >> 6, cc = c & 63;
    const int cp = (c + 511) & 511;            // look-one-back, wraps all 512
    const int hp = cp >> 6, ccp = cp & 63;
    const u16* __restrict__ stm = g_st + (size_t)m * 8 * 4096;
    if (tid < 128) {
        const int hh = (tid < 64) ? h : hp;
        const int cq = (tid < 64) ? cc : ccp;
        tk[tid] = (int)stm[hh * 4096 + cq * 64 + (tid & 63)] & 4095;
    }
    __syncthreads();
    const float* __restrict__ qkm = g_qk32 + ((size_t)m << 18);
    for (int idx = tid; idx < 128 * 16; idx += 256) {
        const int j = idx >> 4, f4 = idx & 15;
        *(float4*)&ks[j * 68 + f4 * 4] =
            *(const float4*)&qkm[((size_t)tk[j] << 6) + f4 * 4];
    }
    __syncthreads();
    if (tid < 128) {
        float ss = 0.f;
        for (int f = 0; f < 64; f++) { const float vv = ks[tid * 68 + f]; ss += vv * vv; }
        rnorm[tid] = 1.0f / fmaxf(sqrtf(ss), 1e-12f);
    }
    __syncthreads();
    const int r = tid & 63, g = tid >> 6;
    const int myq = tk[r];
    float mx = -3.4e38f, s = 0.f;
#pragma unroll 2
    for (int jb = g * 32; jb < g * 32 + 32; jb += 4) {
        float a0 = 0.f, a1 = 0.f, a2 = 0.f, a3 = 0.f;
#pragma unroll
        for (int f4 = 0; f4 < 16; f4++) {
            const float4 q4 = *(const float4*)&ks[r * 68 + f4 * 4];
            const float4 k0 = *(const float4*)&ks[(jb + 0) * 68 + f4 * 4];
            const float4 k1 = *(const float4*)&ks[(jb + 1) * 68 + f4 * 4];
            const float4 k2 = *(const float4*)&ks[(jb + 2) * 68 + f4 * 4];
            const float4 k3 = *(const float4*)&ks[(jb + 3) * 68 + f4 * 4];
            a0 += q4.x * k0.x + q4.y * k0.y + q4.z * k0.z + q4.w * k0.w;
            a1 += q4.x * k1.x + q4.y * k1.y + q4.z * k1.z + q4.w * k1.w;
            a2 += q4.x * k2.x + q4.y * k2.y + q4.z * k2.z + q4.w * k2.w;
            a3 += q4.x * k3.x + q4.y * k3.y + q4.z * k3.z + q4.w * k3.w;
        }
        float dv[4];
        dv[0] = (myq == tk[jb + 0]) ? -50000.f
                : fminf(fmaxf(a0 * rnorm[jb + 0] * 0.125f, -30.f), 30.f);
        dv[1] = (myq == tk[jb + 1]) ? -50000.f
                : fminf(fmaxf(a1 * rnorm[jb + 1] * 0.125f, -30.f), 30.f);
        dv[2] = (myq == tk[jb + 2]) ? -50000.f
                : fminf(fmaxf(a2 * rnorm[jb + 2] * 0.125f, -30.f), 30.f);
        dv[3] = (myq == tk[jb + 3]) ? -50000.f
                : fminf(fmaxf(a3 * rnorm[jb + 3] * 0.125f, -30.f), 30.f);
#pragma unroll
        for (int u = 0; u < 4; u++) {
            const float nm = fmaxf(mx, dv[u]);
            s = s * __expf(mx - nm) + __expf(dv[u] - nm);
            mx = nm;
        }
    }
    part_m[r * 4 + g] = mx;
    part_s[r * 4 + g] = s;
    __syncthreads();
    if (tid < 64) {
        float m2 = -3.4e38f;
#pragma unroll
        for (int g2 = 0; g2 < 4; g2++) m2 = fmaxf(m2, part_m[tid * 4 + g2]);
        float s2 = 0.f;
#pragma unroll
        for (int g2 = 0; g2 < 4; g2++)
            s2 += part_s[tid * 4 + g2] * __expf(part_m[tid * 4 + g2] - m2);
        g_logits[((size_t)m * 8 + h) * 4096 + tk[tid]] = m2 + __logf(s2);
    }
}

// ---------------------------------------------------------------------------
// Kernel 5: round-combination softmax over the 8 hash rounds per (m, t).
// ---------------------------------------------------------------------------
__global__ __launch_bounds__(256) void round_probs()
{
    const int idx = blockIdx.x * 256 + threadIdx.x;  // m*4096 + t
    const int m = idx >> 12, t = idx & 4095;
    float l[8], mx = -3.4e38f;
#pragma unroll
    for (int h = 0; h < 8; h++) {
        l[h] = g_logits[((size_t)m * 8 + h) * 4096 + t];
        mx = fmaxf(mx, l[h]);
    }
    float s = 0.f;
#pragma unroll
    for (int h = 0; h < 8; h++) { l[h] = __expf(l[h] - mx); s += l[h]; }
    const float inv = 1.0f / s;
#pragma unroll
    for (int h = 0; h < 8; h++)
        g_probs[((size_t)m * 8 + h) * 4096 + t] = l[h] * inv;
}

// ---------------------------------------------------------------------------
// Kernel 6: per-chunk attention output, weighted by round prob, scattered
// into g_ctx via fp32 atomics. grid 16384, block 256.
// ---------------------------------------------------------------------------
__global__ __launch_bounds__(256) void attn_out()
{
    __shared__ __align__(16) float ks[128 * 68];
    __shared__ __align__(16) float vs[128 * 68];
    __shared__ float pmat[64 * 129];
    __shared__ float rnorm[128];
    __shared__ int tk[128];
    const int tid = threadIdx.x;
    const int bid = blockIdx.x;
    const int m = bid >> 9, c = bid & 511;
    const int h = c >> 6, cc = c & 63;
    const int cp = (c + 511) & 511;
    const int hp = cp >> 6, ccp = cp & 63;
    const u16* __restrict__ stm = g_st + (size_t)m * 8 * 4096;
    if (tid < 128) {
        const int hh = (tid < 64) ? h : hp;
        const int cq = (tid < 64) ? cc : ccp;
        tk[tid] = (int)stm[hh * 4096 + cq * 64 + (tid & 63)] & 4095;
    }
    __syncthreads();
    const float* __restrict__ qkm = g_qk32 + ((size_t)m << 18);
    const float* __restrict__ vm = g_v32 + ((size_t)m << 18);
    for (int idx = tid; idx < 128 * 16; idx += 256) {
        const int j = idx >> 4, f4 = idx & 15;
        const size_t so = ((size_t)tk[j] << 6) + f4 * 4;
        *(float4*)&ks[j * 68 + f4 * 4] = *(const float4*)&qkm[so];
        *(float4*)&vs[j * 68 + f4 * 4] = *(const float4*)&vm[so];
    }
    __syncthreads();
    if (tid < 128) {
        float ss = 0.f;
        for (int f = 0; f < 64; f++) { const float vv = ks[tid * 68 + f]; ss += vv * vv; }
        rnorm[tid] = 1.0f / fmaxf(sqrtf(ss), 1e-12f);
    }
    __syncthreads();
    const int r = tid & 63, g = tid >> 6;
    const int myq = tk[r];
    const float lse = g_logits[((size_t)m * 8 + h) * 4096 + myq];
#pragma unroll 2
    for (int jb = g * 32; jb < g * 32 + 32; jb += 4) {
        float a0 = 0.f, a1 = 0.f, a2 = 0.f, a3 = 0.f;
#pragma unroll
        for (int f4 = 0; f4 < 16; f4++) {
            const float4 q4 = *(const float4*)&ks[r * 68 + f4 * 4];
            const float4 k0 = *(const float4*)&ks[(jb + 0) * 68 + f4 * 4];
            const float4 k1 = *(const float4*)&ks[(jb + 1) * 68 + f4 * 4];
            const float4 k2 = *(const float4*)&ks[(jb + 2) * 68 + f4 * 4];
            const float4 k3 = *(const float4*)&ks[(jb + 3) * 68 + f4 * 4];
            a0 += q4.x * k0.x + q4.y * k0.y + q4.z * k0.z + q4.w * k0.w;
            a1 += q4.x * k1.x + q4.y * k1.y + q4.z * k1.z + q4.w * k1.w;
            a2 += q4.x * k2.x + q4.y * k2.y + q4.z * k2.z + q4.w * k2.w;
            a3 += q4.x * k3.x + q4.y * k3.y + q4.z * k3.z + q4.w * k3.w;
        }
        const float d0 = (myq == tk[jb + 0]) ? -50000.f
                : fminf(fmaxf(a0 * rnorm[jb + 0] * 0.125f, -30.f), 30.f);
        const float d1 = (myq == tk[jb + 1]) ? -50000.f
                : fminf(fmaxf(a1 * rnorm[jb + 1] * 0.125f, -30.f), 30.f);
        const float d2 = (myq == tk[jb + 2]) ? -50000.f
                : fminf(fmaxf(a2 * rnorm[jb + 2] * 0.125f, -30.f), 30.f);
        const float d3 = (myq == tk[jb + 3]) ? -50000.f
                : fminf(fmaxf(a3 * rnorm[jb + 3] * 0.125f, -30.f), 30.f);
        pmat[r * 129 + jb + 0] = __expf(d0 - lse);
        pmat[r * 129 + jb + 1] = __expf(d1 - lse);
        pmat[r * 129 + jb + 2] = __expf(d2 - lse);
        pmat[r * 129 + jb + 3] = __expf(d3 - lse);
    }
    __syncthreads();
    // bo: thread (r, g) computes dims [g*16, g*16+16) of row r over 128 keys
    const int dbase = g * 16;
    float4 o0 = {0, 0, 0, 0}, o1 = {0, 0, 0, 0}, o2 = {0, 0, 0, 0}, o3 = {0, 0, 0, 0};
    for (int j = 0; j < 128; j++) {
        const float pj = pmat[r * 129 + j];
        const float4 v0 = *(const float4*)&vs[j * 68 + dbase + 0];
        const float4 v1 = *(const float4*)&vs[j * 68 + dbase + 4];
        const float4 v2 = *(const float4*)&vs[j * 68 + dbase + 8];
        const float4 v3 = *(const float4*)&vs[j * 68 + dbase + 12];
        o0.x += pj * v0.x; o0.y += pj * v0.y; o0.z += pj * v0.z; o0.w += pj * v0.w;
        o1.x += pj * v1.x; o1.y += pj * v1.y; o1.z += pj * v1.z; o1.w += pj * v1.w;
        o2.x += pj * v2.x; o2.y += pj * v2.y; o2.z += pj * v2.z; o2.w += pj * v2.w;
        o3.x += pj * v3.x; o3.y += pj * v3.y; o3.z += pj * v3.z; o3.w += pj * v3.w;
    }
    const float wgt = g_probs[((size_t)m * 8 + h) * 4096 + myq];
    float* cd = g_ctx + ((size_t)(m >> 4) * 4096 + myq) * 1024 + (m & 15) * 64 + dbase;
    atomicAdd(&cd[0],  wgt * o0.x); atomicAdd(&cd[1],  wgt * o0.y);
    atomicAdd(&cd[2],  wgt * o0.z); atomicAdd(&cd[3],  wgt * o0.w);
    atomicAdd(&cd[4],  wgt * o1.x); atomicAdd(&cd[5],  wgt * o1.y);
    atomicAdd(&cd[6],  wgt * o1.z); atomicAdd(&cd[7],  wgt * o1.w);
    atomicAdd(&cd[8],  wgt * o2.x); atomicAdd(&cd[9],  wgt * o2.y);
    atomicAdd(&cd[10], wgt * o2.z); atomicAdd(&cd[11], wgt * o2.w);
    atomicAdd(&cd[12], wgt * o3.x); atomicAdd(&cd[13], wgt * o3.y);
    atomicAdd(&cd[14], wgt * o3.z); atomicAdd(&cd[15], wgt * o3.w);
}

// ---------------------------------------------------------------------------
// Kernel 7: out = ctx @ w_out^T + b_out  (fp32 -> fp32 out). grid (128,16)
// ---------------------------------------------------------------------------
__global__ __launch_bounds__(256) void out_gemm(
    const float* __restrict__ w_out, const float* __restrict__ b_out,
    float* __restrict__ out)
{
    __shared__ __align__(16) float As[32][68];
    __shared__ __align__(16) float Ws[32][68];
    const int tid = threadIdx.x;
    const int bm = blockIdx.x, bn = blockIdx.y;
    const int row0 = bm * 64, col0 = bn * 64;
    const int tx = tid & 15, ty = tid >> 4;
    const int lr = tid >> 2;
    const int lk = (tid & 3) * 8;
    float acc[4][4] = {};

    for (int k0 = 0; k0 < 1024; k0 += 32) {
        float av[8], wv[8];
        *(float4*)&av[0] = *(const float4*)(g_ctx + (size_t)(row0 + lr) * 1024 + k0 + lk);
        *(float4*)&av[4] = *(const float4*)(g_ctx + (size_t)(row0 + lr) * 1024 + k0 + lk + 4);
        *(float4*)&wv[0] = *(const float4*)(w_out + (size_t)(col0 + lr) * 1024 + k0 + lk);
        *(float4*)&wv[4] = *(const float4*)(w_out + (size_t)(col0 + lr) * 1024 + k0 + lk + 4);
        __syncthreads();
#pragma unroll
        for (int q = 0; q < 8; q++) { As[lk + q][lr] = av[q]; Ws[lk + q][lr] = wv[q]; }
        __syncthreads();
#pragma unroll
        for (int kk = 0; kk < 32; kk++) {
            const float4 a = *(const float4*)&As[kk][ty * 4];
            const float4 b = *(const float4*)&Ws[kk][tx * 4];
            const float aa[4] = {a.x, a.y, a.z, a.w};
            const float bb[4] = {b.x, b.y, b.z, b.w};
#pragma unroll
            for (int i = 0; i < 4; i++)
#pragma unroll
                for (int j = 0; j < 4; j++)
                    acc[i][j] = fmaf(aa[i], bb[j], acc[i][j]);
        }
    }
#pragma unroll
    for (int i = 0; i < 4; i++) {
        const int row = row0 + ty * 4 + i;
#pragma unroll
        for (int j = 0; j < 4; j++) {
            const int col = col0 + tx * 4 + j;
            out[(size_t)row * 1024 + col] = acc[i][j] + b_out[col];
        }
    }
}

// ---------------------------------------------------------------------------
extern "C" void kernel_launch(void* const* d_in, const int* in_sizes, int n_in,
                              void* d_out, int out_size, void* d_ws, size_t ws_size,
                              hipStream_t stream)
{
    (void)in_sizes; (void)n_in; (void)out_size; (void)d_ws; (void)ws_size;
    const float* x     = (const float*)d_in[0];
    const float* w_qk  = (const float*)d_in[1];
    const float* w_v   = (const float*)d_in[2];
    const float* w_out = (const float*)d_in[3];
    const float* b_out = (const float*)d_in[4];
    const float* rot   = (const float*)d_in[5];

    zero_ctx<<<8192, 256, 0, stream>>>();
    qkv_hash_gemm<<<dim3(128, 32), 256, 0, stream>>>(x, w_qk, w_v, rot);
    sort_kernel<<<256, 256, 0, stream>>>();
    attn_lse<<<16384, 256, 0, stream>>>();
    round_probs<<<512, 256, 0, stream>>>();
    attn_out<<<16384, 256, 0, stream>>>();
    out_gemm<<<dim3(128, 16), 256, 0, stream>>>(w_out, b_out, (float*)d_out);
}